// Round 6
// baseline (809.092 us; speedup 1.0000x reference)
//
#include <hip/hip_runtime.h>

#define TT 1024
#define LOG2E 1.4426950408889634f
#define LN2   0.6931471805599453f

typedef __attribute__((ext_vector_type(2))) float f32x2;
typedef __attribute__((ext_vector_type(4))) float f32x4;
typedef __attribute__((ext_vector_type(2))) _Float16 half2_t;
typedef __attribute__((ext_vector_type(4))) _Float16 half4;

#if __has_builtin(__builtin_amdgcn_exp2f)
#define EXP2F(x) __builtin_amdgcn_exp2f(x)
#else
#define EXP2F(x) exp2f(x)
#endif
#if __has_builtin(__builtin_amdgcn_logf)
#define LOG2F(x) __builtin_amdgcn_logf(x)
#else
#define LOG2F(x) log2f(x)
#endif
#define RCPF(x) __builtin_amdgcn_rcpf(x)
#define MED3(x, lo, hi) __builtin_amdgcn_fmed3f((x), (lo), (hi))

// clamp both elements to [-5,5] (1 v_med3_f32 per element)
__device__ inline f32x2 clamp5(const f32x2 v) {
    return (f32x2){MED3(v.x, -5.f, 5.f), MED3(v.y, -5.f, 5.f)};
}

// [7/6] Pade of tanh: N(u)=u(u^6+378u^4+17325u^2+135135),
// D(u)=28u^6+3150u^4+62370u^2+135135. All-positive D => no pole.
// |err| <= ~2e-4 for clamped |u|<=5. 8 packable ops.
__device__ inline void pade76(const f32x2 u, f32x2& N, f32x2& D) {
    const f32x2 u2 = u * u;
    f32x2 t = u2 + 378.0f;
    t = __builtin_elementwise_fma(u2, t, (f32x2)17325.0f);
    t = __builtin_elementwise_fma(u2, t, (f32x2)135135.0f);
    N = u * t;
    f32x2 d = __builtin_elementwise_fma(u2, (f32x2)28.0f, (f32x2)3150.0f);
    d = __builtin_elementwise_fma(u2, d, (f32x2)62370.0f);
    D = __builtin_elementwise_fma(u2, d, (f32x2)135135.0f);
}

// Gates computed TRANSPOSED via v_mfma_f32_16x16x16f16 (D layout == B layout:
// updated h feeds the next step's B fragment directly — no LDS in recurrence).
//
// Round-6 change (trans-pipe-bound: 28 exp/rcp x 16cyc = the 77% VALUBusy):
// replace ALL exponentials with the pole-free [7/6] Pade rational of tanh.
//   sigmoid(a) = (D(u)+N(u))/(2 D(u)) at u = a/2  (1/2 folded into weights)
//   c' = sig_f*c + sig_i*tanh(g)  -> ONE merged fraction, ONE rcp
//   h  = sig_o*tanh(c')           -> ONE merged fraction, ONE rcp
// Only 8 rcp/step remain on the trans pipe; everything else is fma/mul/add
// packed pairwise over independent rows (v_pk_*_f32). Inputs clamped to +-5
// (v_med3), err <= 2e-4 << f16-h quantization.
__global__ __launch_bounds__(256, 2)
void lstm_head_kernel(const float* __restrict__ x,
                      const float* __restrict__ W_ih,
                      const float* __restrict__ W_hh,
                      const float* __restrict__ b_ih,
                      const float* __restrict__ b_hh,
                      const float* __restrict__ W1,
                      const float* __restrict__ b1,
                      const float* __restrict__ W2,
                      const float* __restrict__ b2,
                      float* __restrict__ out)
{
    __shared__ float lds_f[4][16 * 17];   // final h fp32 staging for the head

    const int tid  = threadIdx.x;
    const int wib  = tid >> 6;
    const int lane = tid & 63;
    const int n    = lane & 15;           // batch within tile (and A-row m)
    const int q    = lane >> 4;           // quadrant
    const int batch0 = (blockIdx.x * 4 + wib) * 16;

    // ---- fixed per-lane constants ----
    // Gates i,f,o pre-scaled by 0.5 (sigmoid-as-tanh(u/2)); g unscaled.
    half4 wfrag[4];        // A fragments: scaled W_hh rows g*16 + n, k = q*4+i
    f32x2 wih[4][2];       // scaled W_ih, row-pairs (r0,r1) / (r2,r3)
    f32x2 bias[4][2];      // scaled (b_ih + b_hh)
    #pragma unroll
    for (int g = 0; g < 4; ++g) {
        const float sc = (g == 2) ? 1.0f : 0.5f;
        const int arow = g * 16 + n;               // A: m = lane&15
        half4 wf;
        #pragma unroll
        for (int i = 0; i < 4; ++i)
            wf[i] = (_Float16)(W_hh[arow * 16 + (q * 4 + i)] * sc);
        wfrag[g] = wf;
        #pragma unroll
        for (int p = 0; p < 2; ++p) {
            const int row0 = g * 16 + q * 4 + 2 * p;
            wih[g][p]  = (f32x2){W_ih[row0] * sc, W_ih[row0 + 1] * sc};
            bias[g][p] = (f32x2){(b_ih[row0] + b_hh[row0]) * sc,
                                 (b_ih[row0 + 1] + b_hh[row0 + 1]) * sc};
        }
    }

    half4 hfrag = {(_Float16)0.f, (_Float16)0.f, (_Float16)0.f, (_Float16)0.f};
    f32x2 Cs[2] = {(f32x2){0.f, 0.f}, (f32x2){0.f, 0.f}};   // cell state (plain)
    f32x2 hv[2] = {(f32x2){0.f, 0.f}, (f32x2){0.f, 0.f}};   // last h (fp32)

    const float* xp = x + (size_t)(batch0 + n) * TT;   // quads read same addr (broadcast)

    for (int t4 = 0; t4 < TT; t4 += 4) {
        const float4 xv = *(const float4*)(xp + t4);
        const float xs4[4] = {xv.x, xv.y, xv.z, xv.w};

        #pragma unroll
        for (int s = 0; s < 4; ++s) {
            const float xs = xs4[s];
            f32x4 acc[4];
            #pragma unroll
            for (int g = 0; g < 4; ++g) {
                const f32x2 ci0 = __builtin_elementwise_fma(wih[g][0], (f32x2)xs, bias[g][0]);
                const f32x2 ci1 = __builtin_elementwise_fma(wih[g][1], (f32x2)xs, bias[g][1]);
                const f32x4 ci = {ci0.x, ci0.y, ci1.x, ci1.y};
                acc[g] = __builtin_amdgcn_mfma_f32_16x16x16f16(wfrag[g], hfrag, ci, 0, 0, 0);
            }

            half2_t hh[2];
            #pragma unroll
            for (int p = 0; p < 2; ++p) {
                const f32x2 ui = clamp5((f32x2){acc[0][2*p], acc[0][2*p + 1]});
                const f32x2 uf = clamp5((f32x2){acc[1][2*p], acc[1][2*p + 1]});
                const f32x2 vg = clamp5((f32x2){acc[2][2*p], acc[2][2*p + 1]});
                const f32x2 uo = clamp5((f32x2){acc[3][2*p], acc[3][2*p + 1]});

                f32x2 Ni, Di, Nf, Df, Ng, Dg, No, Do;
                pade76(ui, Ni, Di);
                pade76(uf, Nf, Df);
                pade76(vg, Ng, Dg);
                pade76(uo, No, Do);

                // c' = [ (Nf+Df)*c*Di*Dg + (Ni+Di)*Ng*Df ] / (2*Df*Di*Dg)
                const f32x2 Pf   = Nf + Df;
                const f32x2 Pi   = Ni + Di;
                const f32x2 DiDg = Di * Dg;
                const f32x2 numA = (Pf * Cs[p]) * DiDg;
                const f32x2 numB = (Pi * Ng) * Df;
                const f32x2 num  = numA + numB;
                const f32x2 den  = Df * DiDg;
                const f32x2 rd   = (f32x2){RCPF(den.x), RCPF(den.y)} * 0.5f;
                const f32x2 cn   = num * rd;
                Cs[p] = cn;

                // h = (No+Do)*Nc / (2*Do*Dc),  Nc/Dc = tanh(clamp(c'))
                f32x2 Nc, Dc;
                pade76(clamp5(cn), Nc, Dc);
                const f32x2 Po   = No + Do;
                const f32x2 Hn   = Po * Nc;
                const f32x2 den2 = Do * Dc;
                const f32x2 rd2  = (f32x2){RCPF(den2.x), RCPF(den2.y)} * 0.5f;
                const f32x2 h2   = Hn * rd2;
                hv[p] = h2;
                hh[p] = __builtin_bit_cast(half2_t, __builtin_amdgcn_cvt_pkrtz(h2.x, h2.y));
            }
            hfrag = (half4){hh[0].x, hh[0].y, hh[1].x, hh[1].y};
        }
    }

    // ---- head: stage final h (fp32) -> 16 lanes do MLP + log_softmax ----
    float* fh = lds_f[wib];
    #pragma unroll
    for (int p = 0; p < 2; ++p) {
        fh[n * 17 + (q * 4 + 2*p)]     = hv[p].x;
        fh[n * 17 + (q * 4 + 2*p + 1)] = hv[p].y;
    }

    if (lane < 16) {
        const int b = batch0 + lane;
        float hvv[16];
        #pragma unroll
        for (int j = 0; j < 16; ++j) hvv[j] = fh[lane * 17 + j];

        float a1[32];
        #pragma unroll
        for (int u = 0; u < 32; ++u) {
            float s = b1[u];
            #pragma unroll
            for (int j = 0; j < 16; ++j) s = fmaf(W1[u * 16 + j], hvv[j], s);
            a1[u] = fmaxf(s, 0.0f);
        }

        float z[6];
        float m = -1e30f;
        #pragma unroll
        for (int v = 0; v < 6; ++v) {
            float s = b2[v];
            #pragma unroll
            for (int u = 0; u < 32; ++u) s = fmaf(W2[v * 32 + u], a1[u], s);
            z[v] = s;
            m = fmaxf(m, s);
        }
        float se = 0.0f;
        #pragma unroll
        for (int v = 0; v < 6; ++v) se += EXP2F((z[v] - m) * LOG2E);
        const float lse = m + LOG2F(se) * LN2;
        #pragma unroll
        for (int v = 0; v < 6; ++v) out[b * 6 + v] = z[v] - lse;
    }
}

extern "C" void kernel_launch(void* const* d_in, const int* in_sizes, int n_in,
                              void* d_out, int out_size, void* d_ws, size_t ws_size,
                              hipStream_t stream) {
    const float* x    = (const float*)d_in[0];
    const float* W_ih = (const float*)d_in[1];
    const float* W_hh = (const float*)d_in[2];
    const float* b_ih = (const float*)d_in[3];
    const float* b_hh = (const float*)d_in[4];
    const float* W1   = (const float*)d_in[5];
    const float* b1   = (const float*)d_in[6];
    const float* W2   = (const float*)d_in[7];
    const float* b2   = (const float*)d_in[8];
    float* out = (float*)d_out;

    const int B = out_size / 6;          // 32768
    const int nblocks = B / 64;          // 64 batch per block (4 waves x 16)

    hipLaunchKernelGGL(lstm_head_kernel, dim3(nblocks), dim3(256), 0, stream,
                       x, W_ih, W_hh, b_ih, b_hh, W1, b1, W2, b2, out);
}

// Round 7
// 617.043 us; speedup vs baseline: 1.3112x; 1.3112x over previous
//
#include <hip/hip_runtime.h>

#define TT 1024
#define LOG2E 1.4426950408889634f
#define LN2   0.6931471805599453f

typedef __attribute__((ext_vector_type(2))) float f32x2;
typedef __attribute__((ext_vector_type(4))) float f32x4;
typedef __attribute__((ext_vector_type(2))) _Float16 half2_t;
typedef __attribute__((ext_vector_type(4))) _Float16 half4;

#if __has_builtin(__builtin_amdgcn_exp2f)
#define EXP2F(x) __builtin_amdgcn_exp2f(x)
#else
#define EXP2F(x) exp2f(x)
#endif
#if __has_builtin(__builtin_amdgcn_logf)
#define LOG2F(x) __builtin_amdgcn_logf(x)
#else
#define LOG2F(x) log2f(x)
#endif
#define RCPF(x) __builtin_amdgcn_rcpf(x)

// TRUE dual-lane packed fp32 (VOP3P). The compiler scalarizes <2 x float>
// elementwise ops (verified r5/r6: no v_pk_* in codegen, cost scales with
// scalar count) — force them with inline asm. Default asm modifiers give
// natural packed semantics (op_sel_hi=[1,1,1]).
__device__ inline f32x2 pk_fma(f32x2 a, f32x2 b, f32x2 c) {
    f32x2 d;
    asm("v_pk_fma_f32 %0, %1, %2, %3" : "=v"(d) : "v"(a), "v"(b), "v"(c));
    return d;
}
__device__ inline f32x2 pk_add(f32x2 a, f32x2 b) {
    f32x2 d;
    asm("v_pk_add_f32 %0, %1, %2" : "=v"(d) : "v"(a), "v"(b));
    return d;
}
__device__ inline f32x2 pk_mul(f32x2 a, f32x2 b) {
    f32x2 d;
    asm("v_pk_mul_f32 %0, %1, %2" : "=v"(d) : "v"(a), "v"(b));
    return d;
}

// Gates computed TRANSPOSED via v_mfma_f32_16x16x16f16 (D layout == B layout:
// updated h feeds the next step's B fragment directly — no LDS in recurrence).
// Gate domain pre-scaled into exp2 space (i,f,o: -log2e; g: +2log2e; cell kept
// as Cs = 2*log2e*c) and merged reciprocals: 5 exp2 + 2 rcp per element — the
// algebraic floor for an exp-based LSTM cell. All full-rate fp32 arithmetic
// packed pairwise over independent rows via inline-asm v_pk_*_f32.
__global__ __launch_bounds__(256, 2)
void lstm_head_kernel(const float* __restrict__ x,
                      const float* __restrict__ W_ih,
                      const float* __restrict__ W_hh,
                      const float* __restrict__ b_ih,
                      const float* __restrict__ b_hh,
                      const float* __restrict__ W1,
                      const float* __restrict__ b1,
                      const float* __restrict__ W2,
                      const float* __restrict__ b2,
                      float* __restrict__ out)
{
    __shared__ float lds_f[4][16 * 17];   // final h fp32 staging for the head

    const int tid  = threadIdx.x;
    const int wib  = tid >> 6;
    const int lane = tid & 63;
    const int n    = lane & 15;           // batch within tile (and A-row m)
    const int q    = lane >> 4;           // quadrant
    const int batch0 = (blockIdx.x * 4 + wib) * 16;

    const float KG = 2.0f * LOG2E;        // g-gate / cell-domain scale

    // ---- fixed per-lane constants (pre-scaled into exp2 domain) ----
    half4 wfrag[4];        // A fragments: scaled W_hh rows g*16 + n, k = q*4+i
    f32x2 wih[4][2];       // scaled W_ih, row-pairs (r0,r1) / (r2,r3)
    f32x2 bias[4][2];      // scaled (b_ih + b_hh)
    #pragma unroll
    for (int g = 0; g < 4; ++g) {
        const float sc = (g == 2) ? KG : -LOG2E;   // i,f,o -> -log2e; g -> +2log2e
        const int arow = g * 16 + n;               // A: m = lane&15
        half4 wf;
        #pragma unroll
        for (int i = 0; i < 4; ++i)
            wf[i] = (_Float16)(W_hh[arow * 16 + (q * 4 + i)] * sc);
        wfrag[g] = wf;
        #pragma unroll
        for (int p = 0; p < 2; ++p) {
            const int row0 = g * 16 + q * 4 + 2 * p;
            wih[g][p]  = (f32x2){W_ih[row0] * sc, W_ih[row0 + 1] * sc};
            bias[g][p] = (f32x2){(b_ih[row0] + b_hh[row0]) * sc,
                                 (b_ih[row0 + 1] + b_hh[row0 + 1]) * sc};
        }
    }

    const f32x2 ONE2  = { 1.0f,  1.0f};
    const f32x2 NONE2 = {-1.0f, -1.0f};
    const f32x2 KG2   = { KG,    KG  };
    const f32x2 NKG2  = {-KG,   -KG  };

    half4 hfrag = {(_Float16)0.f, (_Float16)0.f, (_Float16)0.f, (_Float16)0.f};
    f32x2 Cs[2] = {(f32x2){0.f, 0.f}, (f32x2){0.f, 0.f}};   // scaled cell state
    f32x2 hv[2] = {(f32x2){0.f, 0.f}, (f32x2){0.f, 0.f}};   // last h (fp32)

    const float* xp = x + (size_t)(batch0 + n) * TT;   // quads read same addr (broadcast)

    for (int t4 = 0; t4 < TT; t4 += 4) {
        const float4 xv = *(const float4*)(xp + t4);
        const float xs4[4] = {xv.x, xv.y, xv.z, xv.w};

        #pragma unroll
        for (int s = 0; s < 4; ++s) {
            const float xs = xs4[s];
            const f32x2 xs2 = {xs, xs};
            f32x4 acc[4];
            #pragma unroll
            for (int g = 0; g < 4; ++g) {
                const f32x2 ci0 = pk_fma(wih[g][0], xs2, bias[g][0]);
                const f32x2 ci1 = pk_fma(wih[g][1], xs2, bias[g][1]);
                const f32x4 ci = {ci0.x, ci0.y, ci1.x, ci1.y};
                acc[g] = __builtin_amdgcn_mfma_f32_16x16x16f16(wfrag[g], hfrag, ci, 0, 0, 0);
            }

            half2_t hh[2];
            #pragma unroll
            for (int p = 0; p < 2; ++p) {
                // ei=e^{-ai}, ef=e^{-af}, eg=e^{2ag}, eo=e^{-ao} (scales pre-folded)
                const f32x2 ei = {EXP2F(acc[0][2*p]), EXP2F(acc[0][2*p + 1])};
                const f32x2 ef = {EXP2F(acc[1][2*p]), EXP2F(acc[1][2*p + 1])};
                const f32x2 eg = {EXP2F(acc[2][2*p]), EXP2F(acc[2][2*p + 1])};
                const f32x2 eo = {EXP2F(acc[3][2*p]), EXP2F(acc[3][2*p + 1])};

                // c' = c/(1+ef) + (eg-1)/((1+ei)(eg+1))  [scaled by KG]
                const f32x2 pei = pk_add(ei, ONE2);
                const f32x2 pef = pk_add(ef, ONE2);
                const f32x2 egp = pk_add(eg, ONE2);
                const f32x2 egm = pk_fma(KG2, eg, NKG2);    // KG*(eg-1)
                const f32x2 P   = pk_mul(pei, egp);
                const f32x2 D   = pk_mul(pef, P);
                const f32x2 t2  = pk_mul(pef, egm);
                const f32x2 num = pk_fma(Cs[p], P, t2);
                const f32x2 rD  = {RCPF(D.x), RCPF(D.y)};
                const f32x2 Cn  = pk_mul(num, rD);
                Cs[p] = Cn;

                // h = (ec-1)/((1+eo)(ec+1)),  ec = exp2(Cn)
                const f32x2 ec  = {EXP2F(Cn.x), EXP2F(Cn.y)};
                const f32x2 peo = pk_add(eo, ONE2);
                const f32x2 ecp = pk_add(ec, ONE2);
                const f32x2 ecm = pk_add(ec, NONE2);
                const f32x2 D2  = pk_mul(peo, ecp);
                const f32x2 rD2 = {RCPF(D2.x), RCPF(D2.y)};
                const f32x2 h2  = pk_mul(ecm, rD2);
                hv[p] = h2;
                hh[p] = __builtin_bit_cast(half2_t, __builtin_amdgcn_cvt_pkrtz(h2.x, h2.y));
            }
            hfrag = (half4){hh[0].x, hh[0].y, hh[1].x, hh[1].y};
        }
    }

    // ---- head: stage final h (fp32) -> 16 lanes do MLP + log_softmax ----
    float* fh = lds_f[wib];
    #pragma unroll
    for (int p = 0; p < 2; ++p) {
        fh[n * 17 + (q * 4 + 2*p)]     = hv[p].x;
        fh[n * 17 + (q * 4 + 2*p + 1)] = hv[p].y;
    }

    if (lane < 16) {
        const int b = batch0 + lane;
        float hvv[16];
        #pragma unroll
        for (int j = 0; j < 16; ++j) hvv[j] = fh[lane * 17 + j];

        float a1[32];
        #pragma unroll
        for (int u = 0; u < 32; ++u) {
            float s = b1[u];
            #pragma unroll
            for (int j = 0; j < 16; ++j) s = fmaf(W1[u * 16 + j], hvv[j], s);
            a1[u] = fmaxf(s, 0.0f);
        }

        float z[6];
        float m = -1e30f;
        #pragma unroll
        for (int v = 0; v < 6; ++v) {
            float s = b2[v];
            #pragma unroll
            for (int u = 0; u < 32; ++u) s = fmaf(W2[v * 32 + u], a1[u], s);
            z[v] = s;
            m = fmaxf(m, s);
        }
        float se = 0.0f;
        #pragma unroll
        for (int v = 0; v < 6; ++v) se += EXP2F((z[v] - m) * LOG2E);
        const float lse = m + LOG2F(se) * LN2;
        #pragma unroll
        for (int v = 0; v < 6; ++v) out[b * 6 + v] = z[v] - lse;
    }
}

extern "C" void kernel_launch(void* const* d_in, const int* in_sizes, int n_in,
                              void* d_out, int out_size, void* d_ws, size_t ws_size,
                              hipStream_t stream) {
    const float* x    = (const float*)d_in[0];
    const float* W_ih = (const float*)d_in[1];
    const float* W_hh = (const float*)d_in[2];
    const float* b_ih = (const float*)d_in[3];
    const float* b_hh = (const float*)d_in[4];
    const float* W1   = (const float*)d_in[5];
    const float* b1   = (const float*)d_in[6];
    const float* W2   = (const float*)d_in[7];
    const float* b2   = (const float*)d_in[8];
    float* out = (float*)d_out;

    const int B = out_size / 6;          // 32768
    const int nblocks = B / 64;          // 64 batch per block (4 waves x 16)

    hipLaunchKernelGGL(lstm_head_kernel, dim3(nblocks), dim3(256), 0, stream,
                       x, W_ih, W_hh, b_ih, b_hh, W1, b1, W2, b2, out);
}